// Round 11
// baseline (2085.806 us; speedup 1.0000x reference)
//
#include <hip/hip_runtime.h>
#include <hip/hip_bf16.h>

#define B_ 2
#define N_ 1024
#define D_ 768
#define E_ 128
#define H_ 16
#define HD_ 48
#define HDP_ 64

// instrumentation: proj repeated in-kernel (idempotent) to surface in rocprof
#define PROJ_REPS 32

typedef short bf16x8 __attribute__((ext_vector_type(8)));
typedef float f32x4 __attribute__((ext_vector_type(4)));

__device__ __forceinline__ unsigned short f2bf(float f) {
    __hip_bfloat16 h = __float2bfloat16(f);
    return *reinterpret_cast<unsigned short*>(&h);
}
__device__ __forceinline__ float bf2f(unsigned short s) {
    return __uint_as_float(((unsigned int)s) << 16);
}

// ---------------------------------------------------------------------------
// stage one 64-row edge tile into LDS via global_load_lds (XOR-pre-swizzled
// global source, linear LDS dest; read side applies the same XOR).
// ---------------------------------------------------------------------------
__device__ __forceinline__ void stage_tile(const float* __restrict__ edge,
                                           size_t row0, float* etbuf,
                                           int w, int lane)
{
#pragma unroll
    for (int u = 0; u < 8; ++u) {
        const int row = w * 16 + u * 2 + (lane >> 5);
        const int sl = (lane & 31) ^ (row & 7);
        const float* src = edge + (row0 + row) * E_ + (sl << 2);
        float* dst = etbuf + (w * 16 + u * 2) * E_;
        __builtin_amdgcn_global_load_lds(
            (const __attribute__((address_space(1))) void*)src,
            (__attribute__((address_space(3))) void*)dst, 16, 0, 0);
    }
}

// ---------------------------------------------------------------------------
// Kernel 1: FUSED pair-bias stream (blocks 0..2047) + all input conversions
// (blocks 2048..2559, grid-stride). Bias path identical to R10 (measured at
// ~157us = read roofline). Conv blocks backfill the bias tail.
// ---------------------------------------------------------------------------
__global__ __launch_bounds__(256, 2) void bias_conv_kernel(
    const float* __restrict__ edge, const float* __restrict__ lng,
    const float* __restrict__ lnb, const float* __restrict__ Wz,
    const int* __restrict__ mask, unsigned short* __restrict__ bias,
    const float* __restrict__ node, const float* __restrict__ kin,
    const float* __restrict__ Wq, const float* __restrict__ Wk,
    const float* __restrict__ Wv, const float* __restrict__ Wg,
    const float* __restrict__ Wo,
    unsigned short* __restrict__ nb, unsigned short* __restrict__ kb,
    unsigned short* __restrict__ WqB, unsigned short* __restrict__ WkB,
    unsigned short* __restrict__ WvB, unsigned short* __restrict__ WgB,
    unsigned short* __restrict__ Whi, unsigned short* __restrict__ Wlo,
    unsigned short* __restrict__ qp, unsigned short* __restrict__ kp)
{
    const int tid = threadIdx.x;
    const int lane = tid & 63;
    const int w = tid >> 6;
    const int lr = lane & 15, lg = lane >> 4;

    __shared__ __align__(16) float et[2][64 * E_];

    if (blockIdx.x >= 2048) {
        // ---- conversion path: 512 blocks grid-striding 1589248 float4-units
        const int c = blockIdx.x - 2048;
        for (int u = c * 256 + tid; u < 1589248; u += 131072) {
            if (u < 786432) {
                const int y01 = u / 393216;
                const int idx4 = (u - y01 * 393216) * 4;
                const float* s = y01 ? kin : node;
                unsigned short* d = y01 ? kb : nb;
                const float4 v = *(const float4*)(s + idx4);
                ushort4 o;
                o.x = f2bf(v.x); o.y = f2bf(v.y); o.z = f2bf(v.z); o.w = f2bf(v.w);
                *(ushort4*)(d + idx4) = o;
            } else if (u < 1523712) {
                const int u2 = u - 786432;
                const int w5 = u2 / 147456;
                const int idx4 = (u2 - w5 * 147456) * 4;
                if (w5 < 4) {
                    const float* s = (w5 == 0) ? Wq : (w5 == 1) ? Wk :
                                     (w5 == 2) ? Wv : Wg;
                    unsigned short* d = (w5 == 0) ? WqB : (w5 == 1) ? WkB :
                                        (w5 == 2) ? WvB : WgB;
                    const float4 v = *(const float4*)(s + idx4);
                    ushort4 o;
                    o.x = f2bf(v.x); o.y = f2bf(v.y);
                    o.z = f2bf(v.z); o.w = f2bf(v.w);
                    *(ushort4*)(d + idx4) = o;
                } else {
                    const float4 v = *(const float4*)(Wo + idx4);
                    ushort4 hi, lo;
                    hi.x = f2bf(v.x); lo.x = f2bf(v.x - bf2f(hi.x));
                    hi.y = f2bf(v.y); lo.y = f2bf(v.y - bf2f(hi.y));
                    hi.z = f2bf(v.z); lo.z = f2bf(v.z - bf2f(hi.z));
                    hi.w = f2bf(v.w); lo.w = f2bf(v.w - bf2f(hi.w));
                    *(ushort4*)(Whi + idx4) = hi;
                    *(ushort4*)(Wlo + idx4) = lo;
                }
            } else {
                const int u3 = u - 1523712;
                const int row = u3 >> 1, half = u3 & 1;
                uint4 z = {0u, 0u, 0u, 0u};
                *(uint4*)(qp + ((size_t)row << 6) + 48 + half * 8) = z;
                *(uint4*)(kp + ((size_t)row << 6) + 48 + half * 8) = z;
            }
        }
        return;
    }

    // ---- bias path (identical to R10) ----
    bf16x8 wzf[4];
#pragma unroll
    for (int ks = 0; ks < 4; ++ks)
#pragma unroll
        for (int e = 0; e < 8; ++e)
            wzf[ks][e] = (short)f2bf(Wz[(ks * 32 + lg * 8 + e) * H_ + lr]);

    size_t t = blockIdx.x;
    stage_tile(edge, t * 64, et[0], w, lane);
    __syncthreads();

    for (int it = 0; it < 16; ++it) {
        float* cbuf = et[it & 1];
        float* nbuf = et[(it & 1) ^ 1];
        if (it < 15) stage_tile(edge, (t + 2048) * 64, nbuf, w, lane);

        const int row = w * 16 + lr;
        const int rx = row & 7;
        const float* xr = cbuf + row * E_;
        float x[4][8];
        float s = 0.f, sq = 0.f;
#pragma unroll
        for (int ks = 0; ks < 4; ++ks) {
            const int s0 = ks * 8 + lg * 2;
            const float4 a = *(const float4*)(xr + ((s0 ^ rx) << 2));
            const float4 bb = *(const float4*)(xr + (((s0 + 1) ^ rx) << 2));
            x[ks][0] = a.x; x[ks][1] = a.y; x[ks][2] = a.z; x[ks][3] = a.w;
            x[ks][4] = bb.x; x[ks][5] = bb.y; x[ks][6] = bb.z; x[ks][7] = bb.w;
#pragma unroll
            for (int e = 0; e < 8; ++e) { s += x[ks][e]; sq = fmaf(x[ks][e], x[ks][e], sq); }
        }
        s  += __shfl_xor(s, 16);  s  += __shfl_xor(s, 32);
        sq += __shfl_xor(sq, 16); sq += __shfl_xor(sq, 32);
        const float mean = s * (1.f / 128.f);
        const float var = sq * (1.f / 128.f) - mean * mean;
        const float rs = rsqrtf(var + 1e-5f);
        const float c0 = -mean * rs;

        f32x4 acc = {};
#pragma unroll
        for (int ks = 0; ks < 4; ++ks) {
            bf16x8 af;
#pragma unroll
            for (int e = 0; e < 8; ++e) {
                const int ee = ks * 32 + lg * 8 + e;
                const float zn = fmaf(fmaf(x[ks][e], rs, c0), lng[ee], lnb[ee]);
                af[e] = (short)f2bf(zn);
            }
            acc = __builtin_amdgcn_mfma_f32_16x16x32_bf16(af, wzf[ks], acc, 0, 0, 0);
        }

        const int b = (int)(t >> 14);
        const int i = (int)((t >> 4) & 1023);
        const int j = (int)((t & 15) << 6) + w * 16 + lg * 4;
        const int4 mv = *(const int4*)(mask + b * N_ + j);
        const int* mvp = (const int*)&mv;
        ushort4 pk;
        pk.x = f2bf(acc[0] + (1.f - (float)mvp[0]) * (-1.0e6f));
        pk.y = f2bf(acc[1] + (1.f - (float)mvp[1]) * (-1.0e6f));
        pk.z = f2bf(acc[2] + (1.f - (float)mvp[2]) * (-1.0e6f));
        pk.w = f2bf(acc[3] + (1.f - (float)mvp[3]) * (-1.0e6f));
        *(ushort4*)(bias + (((size_t)((b * H_ + lr) * N_ + i)) << 10) + j) = pk;

        __syncthreads();
        t += 2048;
    }
}

// ---------------------------------------------------------------------------
// Kernel 2: merged projections (R10 proj2), wrapped in PROJ_REPS for rocprof.
// ---------------------------------------------------------------------------
__global__ __launch_bounds__(256) void proj2_kernel(
    const unsigned short* __restrict__ nb, const unsigned short* __restrict__ kb,
    const unsigned short* __restrict__ WqB, const unsigned short* __restrict__ WkB,
    const unsigned short* __restrict__ WvB, const unsigned short* __restrict__ WgB,
    const float* __restrict__ bq,
    unsigned short* __restrict__ qp, unsigned short* __restrict__ kp,
    unsigned short* __restrict__ vT, float* __restrict__ g)
{
    const int pair = blockIdx.z;
    const int lane = threadIdx.x & 63;
    const int w = threadIdx.x >> 6;
    const int wm = w >> 1, wn = w & 1;
    const int lr = lane & 15, lg = lane >> 4;
    const int mbase = blockIdx.x * 64 + wm * 32;
    const int nbase = blockIdx.y * 64 + wn * 32;

    const unsigned short* A  = pair ? kb  : nb;
    const unsigned short* W1 = pair ? WkB : WqB;
    const unsigned short* W2 = pair ? WvB : WgB;

    for (int rep = 0; rep < PROJ_REPS; ++rep) {
        f32x4 acc1[2][2] = {};
        f32x4 acc2[2][2] = {};

        for (int k0 = 0; k0 < D_; k0 += 64) {
            bf16x8 af[2][2], w1f[2][2], w2f[2][2];
#pragma unroll
            for (int hf = 0; hf < 2; ++hf) {
#pragma unroll
                for (int ms = 0; ms < 2; ++ms)
                    af[ms][hf] = *(const bf16x8*)(A + (size_t)(mbase + ms * 16 + lr) * D_ +
                                                  k0 + hf * 32 + lg * 8);
#pragma unroll
                for (int ns = 0; ns < 2; ++ns) {
                    const size_t off = (size_t)(nbase + ns * 16 + lr) * D_ + k0 + hf * 32 + lg * 8;
                    w1f[ns][hf] = *(const bf16x8*)(W1 + off);
                    w2f[ns][hf] = *(const bf16x8*)(W2 + off);
                }
            }
#pragma unroll
            for (int hf = 0; hf < 2; ++hf)
#pragma unroll
                for (int ms = 0; ms < 2; ++ms)
#pragma unroll
                    for (int ns = 0; ns < 2; ++ns) {
                        acc1[ms][ns] = __builtin_amdgcn_mfma_f32_16x16x32_bf16(
                            af[ms][hf], w1f[ns][hf], acc1[ms][ns], 0, 0, 0);
                        if (pair == 0)
                            acc2[ms][ns] = __builtin_amdgcn_mfma_f32_16x16x32_bf16(
                                af[ms][hf], w2f[ns][hf], acc2[ms][ns], 0, 0, 0);
                        else
                            acc2[ns][ms] = __builtin_amdgcn_mfma_f32_16x16x32_bf16(
                                w2f[ns][hf], af[ms][hf], acc2[ns][ms], 0, 0, 0);
                    }
        }

#pragma unroll
        for (int ms = 0; ms < 2; ++ms) {
#pragma unroll
            for (int ns = 0; ns < 2; ++ns) {
#pragma unroll
                for (int r = 0; r < 4; ++r) {
                    {
                        const int tokrow = mbase + ms * 16 + lg * 4 + r;
                        const int dcol = nbase + ns * 16 + lr;
                        const int b = tokrow >> 10, tok = tokrow & 1023;
                        const int h = dcol / HD_, hd = dcol - h * HD_;
                        float v = acc1[ms][ns][r];
                        if (pair == 0) v += bq[dcol];
                        unsigned short* dst = (pair == 0) ? qp : kp;
                        dst[((size_t)((b * H_ + h) * N_ + tok) << 6) + hd] = f2bf(v);
                    }
                    if (pair == 0) {
                        const int tokrow = mbase + ms * 16 + lg * 4 + r;
                        const int dcol = nbase + ns * 16 + lr;
                        g[(size_t)tokrow * D_ + dcol] =
                            1.f / (1.f + __expf(-acc2[ms][ns][r]));
                    } else {
                        const int drow = nbase + ns * 16 + lg * 4 + r;
                        const int tokcol = mbase + ms * 16 + lr;
                        const int b = tokcol >> 10, tok = tokcol & 1023;
                        const int h = drow / HD_, hd = drow - h * HD_;
                        vT[((size_t)((b * H_ + h) * HD_ + hd) << 10) + tok] =
                            f2bf(acc2[ns][ms][r]);
                    }
                }
            }
        }
    }
}

// ---------------------------------------------------------------------------
// Kernel 3: attention (R10 single-pass form, unchanged).
// ---------------------------------------------------------------------------
__global__ __launch_bounds__(256) void attn_kernel(
    const unsigned short* __restrict__ qp, const unsigned short* __restrict__ kp,
    const unsigned short* __restrict__ vT, const unsigned short* __restrict__ bias,
    const float* __restrict__ g,
    unsigned short* __restrict__ Xhi, unsigned short* __restrict__ Xlo)
{
    const int tid = threadIdx.x;
    const int w = tid >> 6;
    const int lane = tid & 63;
    const int lr = lane & 15, lg = lane >> 4;
    const int bh = blockIdx.x >> 6;
    const int it = blockIdx.x & 63;
    const int b = bh >> 4;
    const int h = bh & 15;
    const int i0 = it * 16;
    const float scale = 0.14433756729740643f;

    __shared__ unsigned short pt[4][16][40];
    __shared__ float comb[3][64][13];

    bf16x8 qf0, qf1;
    {
        const unsigned short* qb = qp + (((size_t)bh * N_ + i0 + lr) << 6) + lg * 8;
        qf0 = *(const bf16x8*)qb;
        qf1 = *(const bf16x8*)(qb + 32);
    }

    float li = 0.f;
    f32x4 ov[3] = {};
    const unsigned short* biasrow =
        bias + ((size_t)bh << 20) + ((size_t)(i0 + lr) << 10);

    const int jlo = w * 256;
    for (int j0 = jlo; j0 < jlo + 256; j0 += 32) {
#pragma unroll
        for (int s = 0; s < 2; ++s) {
            const unsigned short* kb =
                kp + (((size_t)bh * N_ + j0 + s * 16 + lr) << 6) + lg * 8;
            bf16x8 k0 = *(const bf16x8*)kb;
            bf16x8 k1 = *(const bf16x8*)(kb + 32);
            f32x4 tacc = {};
            tacc = __builtin_amdgcn_mfma_f32_16x16x32_bf16(k0, qf0, tacc, 0, 0, 0);
            tacc = __builtin_amdgcn_mfma_f32_16x16x32_bf16(k1, qf1, tacc, 0, 0, 0);
            const ushort4 bv = *(const ushort4*)(biasrow + j0 + s * 16 + lg * 4);
            const unsigned short* bvp = (const unsigned short*)&bv;
            float p[4];
#pragma unroll
            for (int r = 0; r < 4; ++r) {
                p[r] = __expf(fmaf(tacc[r], scale, bf2f(bvp[r])));
                li += p[r];
            }
            ushort4 pk;
            pk.x = f2bf(p[0]); pk.y = f2bf(p[1]);
            pk.z = f2bf(p[2]); pk.w = f2bf(p[3]);
            *(ushort4*)&pt[w][lr][s * 16 + lg * 4] = pk;
        }
        bf16x8 pa = *(const bf16x8*)&pt[w][lr][lg * 8];
#pragma unroll
        for (int v = 0; v < 3; ++v) {
            const unsigned short* vb =
                vT + (((size_t)(bh * HD_ + v * 16 + lr)) << 10) + j0 + lg * 8;
            bf16x8 vf = *(const bf16x8*)vb;
            ov[v] = __builtin_amdgcn_mfma_f32_16x16x32_bf16(pa, vf, ov[v], 0, 0, 0);
        }
    }

    if (w > 0) {
        float* cb = &comb[w - 1][lane][0];
#pragma unroll
        for (int v = 0; v < 3; ++v)
#pragma unroll
            for (int r = 0; r < 4; ++r) cb[v * 4 + r] = ov[v][r];
        cb[12] = li;
    }
    __syncthreads();
    if (w == 0) {
#pragma unroll
        for (int s = 0; s < 3; ++s) {
            const float* cb = &comb[s][lane][0];
#pragma unroll
            for (int v = 0; v < 3; ++v)
#pragma unroll
                for (int r = 0; r < 4; ++r) ov[v][r] += cb[v * 4 + r];
            li += cb[12];
        }
        li += __shfl_xor(li, 16);
        li += __shfl_xor(li, 32);
        float lired[4];
#pragma unroll
        for (int r = 0; r < 4; ++r) lired[r] = __shfl(li, lg * 4 + r);

#pragma unroll
        for (int v = 0; v < 3; ++v) {
#pragma unroll
            for (int r = 0; r < 4; ++r) {
                const size_t row = (size_t)(b * N_ + i0 + lg * 4 + r);
                const int col = h * HD_ + v * 16 + lr;
                const float xv = g[row * D_ + col] * (ov[v][r] / lired[r]);
                const unsigned short hi = f2bf(xv);
                const size_t off = row * D_ + col;
                Xhi[off] = hi;
                Xlo[off] = f2bf(xv - bf2f(hi));
            }
        }
    }
}

// ---------------------------------------------------------------------------
// Kernel 4: out = X @ Wo.T via split-bf16 (direct write, no split-K/memset).
// ---------------------------------------------------------------------------
__global__ __launch_bounds__(256) void out_gemm(
    const unsigned short* __restrict__ Xhi, const unsigned short* __restrict__ Xlo,
    const unsigned short* __restrict__ Whi, const unsigned short* __restrict__ Wlo,
    float* __restrict__ out)
{
    const int lane = threadIdx.x & 63;
    const int w = threadIdx.x >> 6;
    const int wm = w >> 1, wn = w & 1;
    const int lr = lane & 15, lg = lane >> 4;
    const int mbase = blockIdx.x * 64 + wm * 32;
    const int nbase = blockIdx.y * 64 + wn * 32;

    f32x4 acc[2][2] = {};
    for (int k0 = 0; k0 < D_; k0 += 32) {
        bf16x8 ah[2], al[2], bh[2], bl[2];
#pragma unroll
        for (int ms = 0; ms < 2; ++ms) {
            const size_t off = (size_t)(mbase + ms * 16 + lr) * D_ + k0 + lg * 8;
            ah[ms] = *(const bf16x8*)(Xhi + off);
            al[ms] = *(const bf16x8*)(Xlo + off);
        }
#pragma unroll
        for (int ns = 0; ns < 2; ++ns) {
            const size_t off = (size_t)(nbase + ns * 16 + lr) * D_ + k0 + lg * 8;
            bh[ns] = *(const bf16x8*)(Whi + off);
            bl[ns] = *(const bf16x8*)(Wlo + off);
        }
#pragma unroll
        for (int ms = 0; ms < 2; ++ms)
#pragma unroll
            for (int ns = 0; ns < 2; ++ns) {
                acc[ms][ns] = __builtin_amdgcn_mfma_f32_16x16x32_bf16(ah[ms], bh[ns], acc[ms][ns], 0, 0, 0);
                acc[ms][ns] = __builtin_amdgcn_mfma_f32_16x16x32_bf16(ah[ms], bl[ns], acc[ms][ns], 0, 0, 0);
                acc[ms][ns] = __builtin_amdgcn_mfma_f32_16x16x32_bf16(al[ms], bh[ns], acc[ms][ns], 0, 0, 0);
            }
    }
#pragma unroll
    for (int ms = 0; ms < 2; ++ms)
#pragma unroll
        for (int ns = 0; ns < 2; ++ns)
#pragma unroll
            for (int r = 0; r < 4; ++r)
                out[(size_t)(mbase + ms * 16 + lg * 4 + r) * D_ + nbase + ns * 16 + lr] =
                    acc[ms][ns][r];
}

// ---------------------------------------------------------------------------
extern "C" void kernel_launch(void* const* d_in, const int* in_sizes, int n_in,
                              void* d_out, int out_size, void* d_ws, size_t ws_size,
                              hipStream_t stream) {
    const float* node = (const float*)d_in[0];
    const float* edge = (const float*)d_in[1];
    const int*   mask = (const int*)d_in[2];
    const float* kin  = (const float*)d_in[3];
    const float* Wq   = (const float*)d_in[4];
    const float* bq   = (const float*)d_in[5];
    const float* Wk   = (const float*)d_in[6];
    const float* Wv   = (const float*)d_in[7];
    const float* Wg   = (const float*)d_in[8];
    const float* lng  = (const float*)d_in[9];
    const float* lnb  = (const float*)d_in[10];
    const float* Wz   = (const float*)d_in[11];
    const float* Wo   = (const float*)d_in[12];
    float* out = (float*)d_out;

    char* ws = (char*)d_ws;
    const size_t qk_bytes = (size_t)B_ * H_ * N_ * HDP_ * 2;
    unsigned short* qp = (unsigned short*)ws;   ws += qk_bytes;
    unsigned short* kp = (unsigned short*)ws;   ws += qk_bytes;
    unsigned short* vT = (unsigned short*)ws;   ws += (size_t)B_ * H_ * HD_ * N_ * 2;
    float* gbuf = (float*)ws;                   ws += (size_t)B_ * N_ * D_ * 4;
    unsigned short* bias = (unsigned short*)ws; ws += (size_t)B_ * H_ * N_ * N_ * 2;
    unsigned short* Xhi = (unsigned short*)ws;  ws += (size_t)B_ * N_ * D_ * 2;
    unsigned short* Xlo = (unsigned short*)ws;  ws += (size_t)B_ * N_ * D_ * 2;
    unsigned short* Whi = (unsigned short*)ws;  ws += (size_t)D_ * D_ * 2;
    unsigned short* Wlo = (unsigned short*)ws;  ws += (size_t)D_ * D_ * 2;
    unsigned short* nb  = (unsigned short*)ws;  ws += (size_t)B_ * N_ * D_ * 2;
    unsigned short* kb  = (unsigned short*)ws;  ws += (size_t)B_ * N_ * D_ * 2;
    unsigned short* WqB = (unsigned short*)ws;  ws += (size_t)D_ * D_ * 2;
    unsigned short* WkB = (unsigned short*)ws;  ws += (size_t)D_ * D_ * 2;
    unsigned short* WvB = (unsigned short*)ws;  ws += (size_t)D_ * D_ * 2;
    unsigned short* WgB = (unsigned short*)ws;  ws += (size_t)D_ * D_ * 2;

    bias_conv_kernel<<<dim3(2560), 256, 0, stream>>>(
        edge, lng, lnb, Wz, mask, bias,
        node, kin, Wq, Wk, Wv, Wg, Wo,
        nb, kb, WqB, WkB, WvB, WgB, Whi, Wlo, qp, kp);
    proj2_kernel<<<dim3(32, 12, 2), 256, 0, stream>>>(
        nb, kb, WqB, WkB, WvB, WgB, bq, qp, kp, vT, gbuf);
    attn_kernel<<<dim3(2048), 256, 0, stream>>>(qp, kp, vT, bias, gbuf, Xhi, Xlo);
    out_gemm<<<dim3(32, 12), 256, 0, stream>>>(Xhi, Xlo, Whi, Wlo, out);
}

// Round 12
// 328.959 us; speedup vs baseline: 6.3406x; 6.3406x over previous
//
#include <hip/hip_runtime.h>
#include <hip/hip_bf16.h>

#define B_ 2
#define N_ 1024
#define D_ 768
#define E_ 128
#define H_ 16
#define HD_ 48
#define HDP_ 64

typedef short bf16x8 __attribute__((ext_vector_type(8)));
typedef float f32x4 __attribute__((ext_vector_type(4)));

__device__ __forceinline__ unsigned short f2bf(float f) {
    __hip_bfloat16 h = __float2bfloat16(f);
    return *reinterpret_cast<unsigned short*>(&h);
}
__device__ __forceinline__ float bf2f(unsigned short s) {
    return __uint_as_float(((unsigned int)s) << 16);
}

// ---------------------------------------------------------------------------
// stage one 64-row edge tile into LDS via global_load_lds (f32, bias kernel)
// ---------------------------------------------------------------------------
__device__ __forceinline__ void stage_tile(const float* __restrict__ edge,
                                           size_t row0, float* etbuf,
                                           int w, int lane)
{
#pragma unroll
    for (int u = 0; u < 8; ++u) {
        const int row = w * 16 + u * 2 + (lane >> 5);
        const int sl = (lane & 31) ^ (row & 7);
        const float* src = edge + (row0 + row) * E_ + (sl << 2);
        float* dst = etbuf + (w * 16 + u * 2) * E_;
        __builtin_amdgcn_global_load_lds(
            (const __attribute__((address_space(1))) void*)src,
            (__attribute__((address_space(3))) void*)dst, 16, 0, 0);
    }
}

// ---------------------------------------------------------------------------
// stage a 64x64 bf16 tile (rows row0.., cols k0..k0+64 of a ld-768 matrix)
// into LDS with chunk-XOR swizzle (chunk' = chunk ^ (row&7)); linear LDS dest.
// Each wave stages its own 16 rows (2 instructions x 1KB).
// ---------------------------------------------------------------------------
__device__ __forceinline__ void stage64(const unsigned short* __restrict__ src,
                                        int row0, int k0,
                                        unsigned short* tile, int w, int lane)
{
#pragma unroll
    for (int u = 0; u < 2; ++u) {
        const int rloc = (lane >> 3);              // 0..7 within instruction
        const int row = w * 16 + u * 8 + rloc;     // row&7 == rloc
        const int ch = (lane & 7) ^ rloc;          // swizzled 8-elem chunk
        const unsigned short* s = src + (size_t)(row0 + row) * D_ + k0 + ch * 8;
        unsigned short* d = tile + (w * 16 + u * 8) * 64;
        __builtin_amdgcn_global_load_lds(
            (const __attribute__((address_space(1))) void*)s,
            (__attribute__((address_space(3))) void*)d, 16, 0, 0);
    }
}

// read a bf16x8 fragment: tile row r, global 8-elem chunk gc (0..7)
#define LDF(tile, r, gc) \
    (*(const bf16x8*)&(tile)[(size_t)(r) * 64 + ((((gc) ^ ((r) & 7))) << 3)])

// ---------------------------------------------------------------------------
// Kernel 1: FUSED pair-bias stream (blocks 0..2047) + input conversions
// (blocks 2048..2559). Identical to R11 (bias at read-roofline ~157us).
// ---------------------------------------------------------------------------
__global__ __launch_bounds__(256, 2) void bias_conv_kernel(
    const float* __restrict__ edge, const float* __restrict__ lng,
    const float* __restrict__ lnb, const float* __restrict__ Wz,
    const int* __restrict__ mask, unsigned short* __restrict__ bias,
    const float* __restrict__ node, const float* __restrict__ kin,
    const float* __restrict__ Wq, const float* __restrict__ Wk,
    const float* __restrict__ Wv, const float* __restrict__ Wg,
    const float* __restrict__ Wo,
    unsigned short* __restrict__ nb, unsigned short* __restrict__ kb,
    unsigned short* __restrict__ WqB, unsigned short* __restrict__ WkB,
    unsigned short* __restrict__ WvB, unsigned short* __restrict__ WgB,
    unsigned short* __restrict__ Whi, unsigned short* __restrict__ Wlo,
    unsigned short* __restrict__ qp, unsigned short* __restrict__ kp)
{
    const int tid = threadIdx.x;
    const int lane = tid & 63;
    const int w = tid >> 6;
    const int lr = lane & 15, lg = lane >> 4;

    __shared__ __align__(16) float et[2][64 * E_];

    if (blockIdx.x >= 2048) {
        const int c = blockIdx.x - 2048;
        for (int u = c * 256 + tid; u < 1589248; u += 131072) {
            if (u < 786432) {
                const int y01 = u / 393216;
                const int idx4 = (u - y01 * 393216) * 4;
                const float* s = y01 ? kin : node;
                unsigned short* d = y01 ? kb : nb;
                const float4 v = *(const float4*)(s + idx4);
                ushort4 o;
                o.x = f2bf(v.x); o.y = f2bf(v.y); o.z = f2bf(v.z); o.w = f2bf(v.w);
                *(ushort4*)(d + idx4) = o;
            } else if (u < 1523712) {
                const int u2 = u - 786432;
                const int w5 = u2 / 147456;
                const int idx4 = (u2 - w5 * 147456) * 4;
                if (w5 < 4) {
                    const float* s = (w5 == 0) ? Wq : (w5 == 1) ? Wk :
                                     (w5 == 2) ? Wv : Wg;
                    unsigned short* d = (w5 == 0) ? WqB : (w5 == 1) ? WkB :
                                        (w5 == 2) ? WvB : WgB;
                    const float4 v = *(const float4*)(s + idx4);
                    ushort4 o;
                    o.x = f2bf(v.x); o.y = f2bf(v.y);
                    o.z = f2bf(v.z); o.w = f2bf(v.w);
                    *(ushort4*)(d + idx4) = o;
                } else {
                    const float4 v = *(const float4*)(Wo + idx4);
                    ushort4 hi, lo;
                    hi.x = f2bf(v.x); lo.x = f2bf(v.x - bf2f(hi.x));
                    hi.y = f2bf(v.y); lo.y = f2bf(v.y - bf2f(hi.y));
                    hi.z = f2bf(v.z); lo.z = f2bf(v.z - bf2f(hi.z));
                    hi.w = f2bf(v.w); lo.w = f2bf(v.w - bf2f(hi.w));
                    *(ushort4*)(Whi + idx4) = hi;
                    *(ushort4*)(Wlo + idx4) = lo;
                }
            } else {
                const int u3 = u - 1523712;
                const int row = u3 >> 1, half = u3 & 1;
                uint4 z = {0u, 0u, 0u, 0u};
                *(uint4*)(qp + ((size_t)row << 6) + 48 + half * 8) = z;
                *(uint4*)(kp + ((size_t)row << 6) + 48 + half * 8) = z;
            }
        }
        return;
    }

    bf16x8 wzf[4];
#pragma unroll
    for (int ks = 0; ks < 4; ++ks)
#pragma unroll
        for (int e = 0; e < 8; ++e)
            wzf[ks][e] = (short)f2bf(Wz[(ks * 32 + lg * 8 + e) * H_ + lr]);

    size_t t = blockIdx.x;
    stage_tile(edge, t * 64, et[0], w, lane);
    __syncthreads();

    for (int it = 0; it < 16; ++it) {
        float* cbuf = et[it & 1];
        float* nbuf = et[(it & 1) ^ 1];
        if (it < 15) stage_tile(edge, (t + 2048) * 64, nbuf, w, lane);

        const int row = w * 16 + lr;
        const int rx = row & 7;
        const float* xr = cbuf + row * E_;
        float x[4][8];
        float s = 0.f, sq = 0.f;
#pragma unroll
        for (int ks = 0; ks < 4; ++ks) {
            const int s0 = ks * 8 + lg * 2;
            const float4 a = *(const float4*)(xr + ((s0 ^ rx) << 2));
            const float4 bb = *(const float4*)(xr + (((s0 + 1) ^ rx) << 2));
            x[ks][0] = a.x; x[ks][1] = a.y; x[ks][2] = a.z; x[ks][3] = a.w;
            x[ks][4] = bb.x; x[ks][5] = bb.y; x[ks][6] = bb.z; x[ks][7] = bb.w;
#pragma unroll
            for (int e = 0; e < 8; ++e) { s += x[ks][e]; sq = fmaf(x[ks][e], x[ks][e], sq); }
        }
        s  += __shfl_xor(s, 16);  s  += __shfl_xor(s, 32);
        sq += __shfl_xor(sq, 16); sq += __shfl_xor(sq, 32);
        const float mean = s * (1.f / 128.f);
        const float var = sq * (1.f / 128.f) - mean * mean;
        const float rs = rsqrtf(var + 1e-5f);
        const float c0 = -mean * rs;

        f32x4 acc = {};
#pragma unroll
        for (int ks = 0; ks < 4; ++ks) {
            bf16x8 af;
#pragma unroll
            for (int e = 0; e < 8; ++e) {
                const int ee = ks * 32 + lg * 8 + e;
                const float zn = fmaf(fmaf(x[ks][e], rs, c0), lng[ee], lnb[ee]);
                af[e] = (short)f2bf(zn);
            }
            acc = __builtin_amdgcn_mfma_f32_16x16x32_bf16(af, wzf[ks], acc, 0, 0, 0);
        }

        const int b = (int)(t >> 14);
        const int i = (int)((t >> 4) & 1023);
        const int j = (int)((t & 15) << 6) + w * 16 + lg * 4;
        const int4 mv = *(const int4*)(mask + b * N_ + j);
        const int* mvp = (const int*)&mv;
        ushort4 pk;
        pk.x = f2bf(acc[0] + (1.f - (float)mvp[0]) * (-1.0e6f));
        pk.y = f2bf(acc[1] + (1.f - (float)mvp[1]) * (-1.0e6f));
        pk.z = f2bf(acc[2] + (1.f - (float)mvp[2]) * (-1.0e6f));
        pk.w = f2bf(acc[3] + (1.f - (float)mvp[3]) * (-1.0e6f));
        *(ushort4*)(bias + (((size_t)((b * H_ + lr) * N_ + i)) << 10) + j) = pk;

        __syncthreads();
        t += 2048;
    }
}

// ---------------------------------------------------------------------------
// Kernel 2: merged projections, LDS-staged (global_load_lds dbuf, XOR swz).
// pair=0: q=node@Wq.T+bq, g=sigmoid(node@Wg.T); pair=1: k=kin@Wk.T, vT=Wv@kin^T.
// Epilogue writes coalesced through LDS (16B/lane; 8|48 so chunks stay in-head).
// ---------------------------------------------------------------------------
__global__ __launch_bounds__(256) void proj2_kernel(
    const unsigned short* __restrict__ nb, const unsigned short* __restrict__ kb,
    const unsigned short* __restrict__ WqB, const unsigned short* __restrict__ WkB,
    const unsigned short* __restrict__ WvB, const unsigned short* __restrict__ WgB,
    const float* __restrict__ bq,
    unsigned short* __restrict__ qp, unsigned short* __restrict__ kp,
    unsigned short* __restrict__ vT, float* __restrict__ g)
{
    const int pair = blockIdx.z;
    const int tid = threadIdx.x;
    const int lane = tid & 63;
    const int w = tid >> 6;
    const int wm = w >> 1, wn = w & 1;
    const int lr = lane & 15, lg = lane >> 4;
    const int mbase = blockIdx.x * 64;     // token rows
    const int nbase = blockIdx.y * 64;     // d cols

    const unsigned short* A  = pair ? kb  : nb;
    const unsigned short* W1 = pair ? WkB : WqB;
    const unsigned short* W2 = pair ? WvB : WgB;

    __shared__ __align__(16) unsigned short st[2][3][64 * 64];  // 48KB

    f32x4 acc1[2][2] = {};
    f32x4 acc2[2][2] = {};

    stage64(A,  mbase, 0, st[0][0], w, lane);
    stage64(W1, nbase, 0, st[0][1], w, lane);
    stage64(W2, nbase, 0, st[0][2], w, lane);
    __syncthreads();

    for (int ks = 0; ks < 12; ++ks) {
        unsigned short (*cb)[4096] = st[ks & 1];
        if (ks < 11) {
            unsigned short (*nbuf)[4096] = st[(ks & 1) ^ 1];
            const int k1 = (ks + 1) * 64;
            stage64(A,  mbase, k1, nbuf[0], w, lane);
            stage64(W1, nbase, k1, nbuf[1], w, lane);
            stage64(W2, nbase, k1, nbuf[2], w, lane);
        }
#pragma unroll
        for (int hf = 0; hf < 2; ++hf) {
            bf16x8 af[2], w1f[2], w2f[2];
#pragma unroll
            for (int ms = 0; ms < 2; ++ms)
                af[ms] = LDF(cb[0], wm * 32 + ms * 16 + lr, hf * 4 + lg);
#pragma unroll
            for (int ns = 0; ns < 2; ++ns) {
                w1f[ns] = LDF(cb[1], wn * 32 + ns * 16 + lr, hf * 4 + lg);
                w2f[ns] = LDF(cb[2], wn * 32 + ns * 16 + lr, hf * 4 + lg);
            }
#pragma unroll
            for (int ms = 0; ms < 2; ++ms)
#pragma unroll
                for (int ns = 0; ns < 2; ++ns) {
                    acc1[ms][ns] = __builtin_amdgcn_mfma_f32_16x16x32_bf16(
                        af[ms], w1f[ns], acc1[ms][ns], 0, 0, 0);
                    if (pair == 0)
                        acc2[ms][ns] = __builtin_amdgcn_mfma_f32_16x16x32_bf16(
                            af[ms], w2f[ns], acc2[ms][ns], 0, 0, 0);
                    else
                        acc2[ns][ms] = __builtin_amdgcn_mfma_f32_16x16x32_bf16(
                            w2f[ns], af[ms], acc2[ns][ms], 0, 0, 0);
                }
        }
        __syncthreads();
    }

    // ---- epilogue: stage C tiles in LDS, then coalesced writes ----
    unsigned short* t1 = &st[0][0][0];          // q or k tile, bf16 [64][64]
    unsigned short* t2 = &st[0][1][0];          // vT tile (pair1), bf16 [64][64]
    float* gt = (float*)&st[0][1][0];           // g tile (pair0), f32 16KB

    float bqv[2] = {0.f, 0.f};
    if (pair == 0) {
#pragma unroll
        for (int ns = 0; ns < 2; ++ns)
            bqv[ns] = bq[nbase + wn * 32 + ns * 16 + lr];
    }

#pragma unroll
    for (int ms = 0; ms < 2; ++ms)
#pragma unroll
        for (int ns = 0; ns < 2; ++ns)
#pragma unroll
            for (int r = 0; r < 4; ++r) {
                const int row = wm * 32 + ms * 16 + lg * 4 + r;   // tok-local
                const int col = wn * 32 + ns * 16 + lr;           // d-local (or d-row for v)
                t1[row * 64 + col] = f2bf(acc1[ms][ns][r] + bqv[ns]);
                if (pair == 0)
                    gt[row * 64 + col] = 1.f / (1.f + __expf(-acc2[ms][ns][r]));
                else {
                    const int drow = wn * 32 + ns * 16 + lg * 4 + r;
                    const int tcol = wm * 32 + ms * 16 + lr;
                    t2[drow * 64 + tcol] = f2bf(acc2[ns][ms][r]);
                }
            }
    __syncthreads();

    const int b = mbase >> 10;
    const int tok0 = mbase & 1023;
    // q/k: 512 chunks of 8 shorts (16B); 8|48 so a chunk never crosses a head
    unsigned short* dst1 = (pair == 0) ? qp : kp;
    for (int c = tid; c < 512; c += 256) {
        const int row = c >> 3, ch = (c & 7) * 8;
        const int colg = nbase + ch;
        const int h = colg / HD_, hd = colg - h * HD_;
        *(uint4*)(dst1 + (((size_t)((b * H_ + h) * N_ + tok0 + row)) << 6) + hd) =
            *(const uint4*)&t1[row * 64 + ch];
    }
    if (pair == 0) {
        for (int c = tid; c < 1024; c += 256) {
            const int row = c >> 4, ch = (c & 15) * 4;
            *(float4*)(g + (size_t)(mbase + row) * D_ + nbase + ch) =
                *(const float4*)&gt[row * 64 + ch];
        }
    } else {
        for (int c = tid; c < 512; c += 256) {
            const int dl = c >> 3, tch = (c & 7) * 8;
            const int dg = nbase + dl;
            const int h = dg / HD_, hd = dg - h * HD_;
            *(uint4*)(vT + (((size_t)((b * H_ + h) * HD_ + hd)) << 10) + tok0 + tch) =
                *(const uint4*)&t2[dl * 64 + tch];
        }
    }
}

// ---------------------------------------------------------------------------
// Kernel 3: attention (unchanged single-pass form).
// ---------------------------------------------------------------------------
__global__ __launch_bounds__(256) void attn_kernel(
    const unsigned short* __restrict__ qp, const unsigned short* __restrict__ kp,
    const unsigned short* __restrict__ vT, const unsigned short* __restrict__ bias,
    const float* __restrict__ g,
    unsigned short* __restrict__ Xhi, unsigned short* __restrict__ Xlo)
{
    const int tid = threadIdx.x;
    const int w = tid >> 6;
    const int lane = tid & 63;
    const int lr = lane & 15, lg = lane >> 4;
    const int bh = blockIdx.x >> 6;
    const int it = blockIdx.x & 63;
    const int b = bh >> 4;
    const int h = bh & 15;
    const int i0 = it * 16;
    const float scale = 0.14433756729740643f;

    __shared__ unsigned short pt[4][16][40];
    __shared__ float comb[3][64][13];

    bf16x8 qf0, qf1;
    {
        const unsigned short* qb = qp + (((size_t)bh * N_ + i0 + lr) << 6) + lg * 8;
        qf0 = *(const bf16x8*)qb;
        qf1 = *(const bf16x8*)(qb + 32);
    }

    float li = 0.f;
    f32x4 ov[3] = {};
    const unsigned short* biasrow =
        bias + ((size_t)bh << 20) + ((size_t)(i0 + lr) << 10);

    const int jlo = w * 256;
    for (int j0 = jlo; j0 < jlo + 256; j0 += 32) {
#pragma unroll
        for (int s = 0; s < 2; ++s) {
            const unsigned short* kb =
                kp + (((size_t)bh * N_ + j0 + s * 16 + lr) << 6) + lg * 8;
            bf16x8 k0 = *(const bf16x8*)kb;
            bf16x8 k1 = *(const bf16x8*)(kb + 32);
            f32x4 tacc = {};
            tacc = __builtin_amdgcn_mfma_f32_16x16x32_bf16(k0, qf0, tacc, 0, 0, 0);
            tacc = __builtin_amdgcn_mfma_f32_16x16x32_bf16(k1, qf1, tacc, 0, 0, 0);
            const ushort4 bv = *(const ushort4*)(biasrow + j0 + s * 16 + lg * 4);
            const unsigned short* bvp = (const unsigned short*)&bv;
            float p[4];
#pragma unroll
            for (int r = 0; r < 4; ++r) {
                p[r] = __expf(fmaf(tacc[r], scale, bf2f(bvp[r])));
                li += p[r];
            }
            ushort4 pk;
            pk.x = f2bf(p[0]); pk.y = f2bf(p[1]);
            pk.z = f2bf(p[2]); pk.w = f2bf(p[3]);
            *(ushort4*)&pt[w][lr][s * 16 + lg * 4] = pk;
        }
        bf16x8 pa = *(const bf16x8*)&pt[w][lr][lg * 8];
#pragma unroll
        for (int v = 0; v < 3; ++v) {
            const unsigned short* vb =
                vT + (((size_t)(bh * HD_ + v * 16 + lr)) << 10) + j0 + lg * 8;
            bf16x8 vf = *(const bf16x8*)vb;
            ov[v] = __builtin_amdgcn_mfma_f32_16x16x32_bf16(pa, vf, ov[v], 0, 0, 0);
        }
    }

    if (w > 0) {
        float* cb = &comb[w - 1][lane][0];
#pragma unroll
        for (int v = 0; v < 3; ++v)
#pragma unroll
            for (int r = 0; r < 4; ++r) cb[v * 4 + r] = ov[v][r];
        cb[12] = li;
    }
    __syncthreads();
    if (w == 0) {
#pragma unroll
        for (int s = 0; s < 3; ++s) {
            const float* cb = &comb[s][lane][0];
#pragma unroll
            for (int v = 0; v < 3; ++v)
#pragma unroll
                for (int r = 0; r < 4; ++r) ov[v][r] += cb[v * 4 + r];
            li += cb[12];
        }
        li += __shfl_xor(li, 16);
        li += __shfl_xor(li, 32);
        float lired[4];
#pragma unroll
        for (int r = 0; r < 4; ++r) lired[r] = __shfl(li, lg * 4 + r);

#pragma unroll
        for (int v = 0; v < 3; ++v) {
#pragma unroll
            for (int r = 0; r < 4; ++r) {
                const size_t row = (size_t)(b * N_ + i0 + lg * 4 + r);
                const int col = h * HD_ + v * 16 + lr;
                const float xv = g[row * D_ + col] * (ov[v][r] / lired[r]);
                const unsigned short hi = f2bf(xv);
                const size_t off = row * D_ + col;
                Xhi[off] = hi;
                Xlo[off] = f2bf(xv - bf2f(hi));
            }
        }
    }
}

// ---------------------------------------------------------------------------
// Kernel 4: out = X @ Wo.T via split-bf16, LDS-staged (same template).
// ---------------------------------------------------------------------------
__global__ __launch_bounds__(256) void out_gemm(
    const unsigned short* __restrict__ Xhi, const unsigned short* __restrict__ Xlo,
    const unsigned short* __restrict__ Whi, const unsigned short* __restrict__ Wlo,
    float* __restrict__ out)
{
    const int tid = threadIdx.x;
    const int lane = tid & 63;
    const int w = tid >> 6;
    const int wm = w >> 1, wn = w & 1;
    const int lr = lane & 15, lg = lane >> 4;
    const int mbase = blockIdx.x * 64;
    const int nbase = blockIdx.y * 64;

    __shared__ __align__(16) unsigned short st[2][4][64 * 64];  // 64KB

    f32x4 acc[2][2] = {};

    stage64(Xhi, mbase, 0, st[0][0], w, lane);
    stage64(Xlo, mbase, 0, st[0][1], w, lane);
    stage64(Whi, nbase, 0, st[0][2], w, lane);
    stage64(Wlo, nbase, 0, st[0][3], w, lane);
    __syncthreads();

    for (int ks = 0; ks < 12; ++ks) {
        unsigned short (*cb)[4096] = st[ks & 1];
        if (ks < 11) {
            unsigned short (*nbuf)[4096] = st[(ks & 1) ^ 1];
            const int k1 = (ks + 1) * 64;
            stage64(Xhi, mbase, k1, nbuf[0], w, lane);
            stage64(Xlo, mbase, k1, nbuf[1], w, lane);
            stage64(Whi, nbase, k1, nbuf[2], w, lane);
            stage64(Wlo, nbase, k1, nbuf[3], w, lane);
        }
#pragma unroll
        for (int hf = 0; hf < 2; ++hf) {
            bf16x8 ah[2], al[2], bh[2], bl[2];
#pragma unroll
            for (int ms = 0; ms < 2; ++ms) {
                ah[ms] = LDF(cb[0], wm * 32 + ms * 16 + lr, hf * 4 + lg);
                al[ms] = LDF(cb[1], wm * 32 + ms * 16 + lr, hf * 4 + lg);
            }
#pragma unroll
            for (int ns = 0; ns < 2; ++ns) {
                bh[ns] = LDF(cb[2], wn * 32 + ns * 16 + lr, hf * 4 + lg);
                bl[ns] = LDF(cb[3], wn * 32 + ns * 16 + lr, hf * 4 + lg);
            }
#pragma unroll
            for (int ms = 0; ms < 2; ++ms)
#pragma unroll
                for (int ns = 0; ns < 2; ++ns) {
                    acc[ms][ns] = __builtin_amdgcn_mfma_f32_16x16x32_bf16(ah[ms], bh[ns], acc[ms][ns], 0, 0, 0);
                    acc[ms][ns] = __builtin_amdgcn_mfma_f32_16x16x32_bf16(ah[ms], bl[ns], acc[ms][ns], 0, 0, 0);
                    acc[ms][ns] = __builtin_amdgcn_mfma_f32_16x16x32_bf16(al[ms], bh[ns], acc[ms][ns], 0, 0, 0);
                }
        }
        __syncthreads();
    }

#pragma unroll
    for (int ms = 0; ms < 2; ++ms)
#pragma unroll
        for (int ns = 0; ns < 2; ++ns)
#pragma unroll
            for (int r = 0; r < 4; ++r)
                out[(size_t)(mbase + wm * 32 + ms * 16 + lg * 4 + r) * D_ +
                    nbase + wn * 32 + ns * 16 + lr] = acc[ms][ns][r];
}

// ---------------------------------------------------------------------------
extern "C" void kernel_launch(void* const* d_in, const int* in_sizes, int n_in,
                              void* d_out, int out_size, void* d_ws, size_t ws_size,
                              hipStream_t stream) {
    const float* node = (const float*)d_in[0];
    const float* edge = (const float*)d_in[1];
    const int*   mask = (const int*)d_in[2];
    const float* kin  = (const float*)d_in[3];
    const float* Wq   = (const float*)d_in[4];
    const float* bq   = (const float*)d_in[5];
    const float* Wk   = (const float*)d_in[6];
    const float* Wv   = (const float*)d_in[7];
    const float* Wg   = (const float*)d_in[8];
    const float* lng  = (const float*)d_in[9];
    const float* lnb  = (const float*)d_in[10];
    const float* Wz   = (const float*)d_in[11];
    const float* Wo   = (const float*)d_in[12];
    float* out = (float*)d_out;

    char* ws = (char*)d_ws;
    const size_t qk_bytes = (size_t)B_ * H_ * N_ * HDP_ * 2;
    unsigned short* qp = (unsigned short*)ws;   ws += qk_bytes;
    unsigned short* kp = (unsigned short*)ws;   ws += qk_bytes;
    unsigned short* vT = (unsigned short*)ws;   ws += (size_t)B_ * H_ * HD_ * N_ * 2;
    float* gbuf = (float*)ws;                   ws += (size_t)B_ * N_ * D_ * 4;
    unsigned short* bias = (unsigned short*)ws; ws += (size_t)B_ * H_ * N_ * N_ * 2;
    unsigned short* Xhi = (unsigned short*)ws;  ws += (size_t)B_ * N_ * D_ * 2;
    unsigned short* Xlo = (unsigned short*)ws;  ws += (size_t)B_ * N_ * D_ * 2;
    unsigned short* Whi = (unsigned short*)ws;  ws += (size_t)D_ * D_ * 2;
    unsigned short* Wlo = (unsigned short*)ws;  ws += (size_t)D_ * D_ * 2;
    unsigned short* nb  = (unsigned short*)ws;  ws += (size_t)B_ * N_ * D_ * 2;
    unsigned short* kb  = (unsigned short*)ws;  ws += (size_t)B_ * N_ * D_ * 2;
    unsigned short* WqB = (unsigned short*)ws;  ws += (size_t)D_ * D_ * 2;
    unsigned short* WkB = (unsigned short*)ws;  ws += (size_t)D_ * D_ * 2;
    unsigned short* WvB = (unsigned short*)ws;  ws += (size_t)D_ * D_ * 2;
    unsigned short* WgB = (unsigned short*)ws;  ws += (size_t)D_ * D_ * 2;

    bias_conv_kernel<<<dim3(2560), 256, 0, stream>>>(
        edge, lng, lnb, Wz, mask, bias,
        node, kin, Wq, Wk, Wv, Wg, Wo,
        nb, kb, WqB, WkB, WvB, WgB, Whi, Wlo, qp, kp);
    proj2_kernel<<<dim3(32, 12, 2), 256, 0, stream>>>(
        nb, kb, WqB, WkB, WvB, WgB, bq, qp, kp, vT, gbuf);
    attn_kernel<<<dim3(2048), 256, 0, stream>>>(qp, kp, vT, bias, gbuf, Xhi, Xlo);
    out_gemm<<<dim3(32, 12), 256, 0, stream>>>(Xhi, Xlo, Whi, Wlo, out);
}